// Round 3
// 496.374 us; speedup vs baseline: 1.3419x; 1.3419x over previous
//
#include <hip/hip_runtime.h>

// (E,B,C,H,W) = (3,8,10,512,512), HIDDEN=256
#define HWQ   262144      // H*W
#define CHW   2621440     // C*H*W
#define BCHW  20971520    // B*C*H*W
#define NTOT  2097152     // B*H*W

#define NBLOCKS 1024
#define BITERS  8         // 1024 blocks * 8 iters * 256 tokens = 2,097,152

typedef __attribute__((ext_vector_type(8))) short short8;  // 8 bf16 (4 VGPRs)
typedef __attribute__((ext_vector_type(4))) float f32x4;

union Frag { uint u[4]; uint4 u4; short8 s; };   // 16B type-pun (union: OK in HIP)

// f32 -> bf16 (RNE), pure C bit-trick (no inline asm; same rounding as
// v_cvt_pk_bf16_f32; compiler emits good code for this — m240).
// Valid for finite inputs (problem data is gaussian/uniform, no inf/nan).
__device__ __forceinline__ uint bf16w(float x) {
    const uint u = __float_as_uint(x);
    return (u + 0x7FFFu + ((u >> 16) & 1u)) >> 16;   // bf16 in low 16 bits
}

// 3-limb split of an f32 pair into packed bf16 words (lo16 = a, hi16 = b).
// v = hi + mid + lo with residual ~2^-24 * |v| (hi/mid subtractions exact).
__device__ __forceinline__ void split_pair(float a, float b,
                                           uint& h, uint& m, uint& l) {
    const uint ha = bf16w(a), hb = bf16w(b);
    h = ha | (hb << 16);
    const float fa = __uint_as_float(ha << 16);
    const float fb = __uint_as_float(hb << 16);
    const float ra = a - fa, rb = b - fb;
    const uint ma = bf16w(ra), mb = bf16w(rb);
    m = ma | (mb << 16);
    const float ga = __uint_as_float(ma << 16);
    const float gb = __uint_as_float(mb << 16);
    l = bf16w(ra - ga) | (bf16w(rb - gb) << 16);
}

// One fused kernel, no d_ws (prior session: d_ws writes corrupt harness state).
// Per block: stage w1(+b1 @ k=30) once into LDS as bf16x3-limb MFMA B-fragments,
// then each wave independently processes 32 tokens/iter:
//   gather x (30 planes, k=30 -> 1.0 for bias, k=31 -> 0) -> 3-limb A-frags
//   -> 16 hidden-tiles x [6 limb-product MFMAs 16x16x32] -> relu -> h@w2 in fp32
//   -> 16-lane butterfly reduce -> argmax -> re-gather selected expert's 10 planes.
// A/B k-layout convention is identical on both operands, so any k-permutation
// cancels; only the m89-verified C/D layout (col=lane&15,row=(lane>>4)*4+reg)
// is relied on.
__global__ __launch_bounds__(512)
void mlp_select_mfma(const float* __restrict__ inputs,
                     const float* __restrict__ w1,
                     const float* __restrict__ b1,
                     const float* __restrict__ w2,
                     const float* __restrict__ b2,
                     float* __restrict__ out0,
                     float* __restrict__ out1) {
    __shared__ uint4 Bfrag[16 * 3 * 64];   // 49,152 B: [ht][limb][lane] 16B frags
    __shared__ float W2s[768];             // w2 copy (256x3)
    __shared__ float Logb[8 * 96];         // per-wave logits staging (32 tok x 3)

    const int tid = threadIdx.x;

    // ---- one-time staging: w1/b1 -> limb B-fragments; w2 -> LDS ----
    for (int idx = tid; idx < 16 * 64; idx += 512) {
        const int ht = idx >> 6, ln = idx & 63;
        const int col = (ht << 4) | (ln & 15);     // hidden unit (B col = lane&15)
        const int kbs = (ln >> 4) << 3;            // k-group base (same conv as A)
        Frag fh, fm, fl;
        #pragma unroll
        for (int jj = 0; jj < 4; ++jj) {
            const int k0 = kbs + 2 * jj, k1 = k0 + 1;
            const float a = (k0 < 30) ? w1[k0 * 256 + col]
                                      : ((k0 == 30) ? b1[col] : 0.f);
            const float b = (k1 < 30) ? w1[k1 * 256 + col]
                                      : ((k1 == 30) ? b1[col] : 0.f);
            split_pair(a, b, fh.u[jj], fm.u[jj], fl.u[jj]);
        }
        const int base = ht * 3 * 64 + ln;
        Bfrag[base]       = fh.u4;
        Bfrag[base + 64]  = fm.u4;
        Bfrag[base + 128] = fl.u4;
    }
    for (int i = tid; i < 768; i += 512) W2s[i] = w2[i];
    __syncthreads();

    const int lane = tid & 63;
    const int wid  = tid >> 6;
    const int l15  = lane & 15;
    const int lg   = lane >> 4;
    const int kb   = lg << 3;

    // per-lane byte offsets of the 8 k-planes this lane loads (A-frag k-slice)
    uint koff[8];
    #pragma unroll
    for (int j = 0; j < 8; ++j) {
        const int k = kb + j;
        const int e = (k >= 20) ? 2 : ((k >= 10) ? 1 : 0);
        const int c = k - e * 10;
        koff[j] = (k < 30) ? (uint)((e * BCHW + c * HWQ) * 4) : 0u;  // k>=30: safe dummy
    }
    const float b20 = b2[0], b21 = b2[1], b22 = b2[2];
    const char* ib = (const char*)inputs;
    char* ob = (char*)out0;

    #pragma unroll 1
    for (int it = 0; it < BITERS; ++it) {
        const int n0 = (blockIdx.x * BITERS + it) * 256 + wid * 32; // wave's 32 tokens
        // 32-token runs never cross a b (2^18) boundary -> b,hw0 uniform per wave
        const uint sbase = (uint)((n0 >> 18) * CHW + (n0 & (HWQ - 1))) * 4u;

        // ---- gather + 3-limb split -> A fragments for 2 16-token tiles ----
        short8 Ah[2], Am[2], Al[2];
        #pragma unroll
        for (int t = 0; t < 2; ++t) {
            const uint vb = sbase + (uint)((t * 16 + l15) * 4);  // A row = lane&15
            float xv[8];
            #pragma unroll
            for (int j = 0; j < 8; ++j)
                xv[j] = *(const float*)(ib + (size_t)(vb + koff[j]));
            if (kb == 24) { xv[6] = 1.f; xv[7] = 0.f; }  // k=30 -> 1.0 (bias), k=31 -> 0
            Frag ch_, cm_, cl_;
            #pragma unroll
            for (int jj = 0; jj < 4; ++jj)
                split_pair(xv[2 * jj], xv[2 * jj + 1],
                           ch_.u[jj], cm_.u[jj], cl_.u[jj]);
            Ah[t] = ch_.s; Am[t] = cm_.s; Al[t] = cl_.s;
        }

        float lacc[2][4][3];
        #pragma unroll
        for (int t = 0; t < 2; ++t)
            #pragma unroll
            for (int r = 0; r < 4; ++r)
                lacc[t][r][0] = lacc[t][r][1] = lacc[t][r][2] = 0.f;

        // ---- 16 hidden-tiles: 6 limb-product MFMAs each (small terms first) ----
        #pragma unroll 4
        for (int ht = 0; ht < 16; ++ht) {
            const uint4* bp = &Bfrag[ht * 3 * 64 + lane];
            Frag bh, bm, bl;
            bh.u4 = bp[0]; bm.u4 = bp[64]; bl.u4 = bp[128];
            const int wcol = ((ht << 4) | l15) * 3;
            const float w20 = W2s[wcol], w21 = W2s[wcol + 1], w22 = W2s[wcol + 2];
            #pragma unroll
            for (int t = 0; t < 2; ++t) {
                f32x4 D = {0.f, 0.f, 0.f, 0.f};
                D = __builtin_amdgcn_mfma_f32_16x16x32_bf16(Al[t], bh.s, D, 0, 0, 0);
                D = __builtin_amdgcn_mfma_f32_16x16x32_bf16(Ah[t], bl.s, D, 0, 0, 0);
                D = __builtin_amdgcn_mfma_f32_16x16x32_bf16(Am[t], bm.s, D, 0, 0, 0);
                D = __builtin_amdgcn_mfma_f32_16x16x32_bf16(Am[t], bh.s, D, 0, 0, 0);
                D = __builtin_amdgcn_mfma_f32_16x16x32_bf16(Ah[t], bm.s, D, 0, 0, 0);
                D = __builtin_amdgcn_mfma_f32_16x16x32_bf16(Ah[t], bh.s, D, 0, 0, 0);
                #pragma unroll
                for (int r = 0; r < 4; ++r) {     // D: token = lg*4+r, hid = ht*16+l15
                    const float hre = fmaxf(D[r], 0.f);
                    lacc[t][r][0] = fmaf(hre, w20, lacc[t][r][0]);
                    lacc[t][r][1] = fmaf(hre, w21, lacc[t][r][1]);
                    lacc[t][r][2] = fmaf(hre, w22, lacc[t][r][2]);
                }
            }
        }

        // ---- butterfly-reduce logits over the 16 hidden-lanes (lg fixed) ----
        #pragma unroll
        for (int t = 0; t < 2; ++t)
            #pragma unroll
            for (int r = 0; r < 4; ++r)
                #pragma unroll
                for (int e = 0; e < 3; ++e) {
                    float v = lacc[t][r][e];
                    v += __shfl_xor(v, 1);
                    v += __shfl_xor(v, 2);
                    v += __shfl_xor(v, 4);
                    v += __shfl_xor(v, 8);
                    lacc[t][r][e] = v;
                }

        if (l15 == 0) {   // one writer lane per quarter-wave -> wave-local staging
            float* lb = &Logb[wid * 96];
            #pragma unroll
            for (int t = 0; t < 2; ++t)
                #pragma unroll
                for (int r = 0; r < 4; ++r) {
                    const int tk = t * 16 + lg * 4 + r;
                    lb[tk * 3 + 0] = lacc[t][r][0];
                    lb[tk * 3 + 1] = lacc[t][r][1];
                    lb[tk * 3 + 2] = lacc[t][r][2];
                }
        }
        // same-wave LDS RAW: writer and readers are the same wave; an
        // in-stream LDS drain suffices (compiler-managed fence, no raw asm).
        __threadfence_block();

        // ---- argmax (first-max semantics) + gather-write selected expert ----
        const int tt = lane & 31;
        const float* lb = &Logb[wid * 96 + tt * 3];
        const float L0 = lb[0] + b20;
        const float L1 = lb[1] + b21;
        const float L2 = lb[2] + b22;
        int sel = 0; float best = L0;
        if (L1 > best) { best = L1; sel = 1; }
        if (L2 > best) { sel = 2; }

        const uint obase = sbase + (uint)(tt * 4);
        const uint ioff  = obase + (uint)sel * (uint)(BCHW * 4);
        const int chalf  = lane >> 5;          // lanes 0-31: c=0..4, 32-63: c=5..9
        #pragma unroll
        for (int cc = 0; cc < 5; ++cc) {
            const uint cofs = (uint)((chalf * 5 + cc) * (HWQ * 4));
            const float v = *(const float*)(ib + (size_t)(ioff + cofs));
            *(float*)(ob + (size_t)(obase + cofs)) = v;
        }
        if (lane < 32) out1[n0 + tt] = (float)sel;
    }
}

extern "C" void kernel_launch(void* const* d_in, const int* in_sizes, int n_in,
                              void* d_out, int out_size, void* d_ws, size_t ws_size,
                              hipStream_t stream) {
    const float* inputs = (const float*)d_in[0];   // (3,8,10,512,512)
    const float* w1     = (const float*)d_in[1];   // (30,256)
    const float* b1     = (const float*)d_in[2];   // (256,)
    const float* w2     = (const float*)d_in[3];   // (256,3)
    const float* b2     = (const float*)d_in[4];   // (3,)

    float* out0 = (float*)d_out;           // (8,10,512,512)
    float* out1 = out0 + BCHW;             // (8,512,512) selections as float

    mlp_select_mfma<<<NBLOCKS, 512, 0, stream>>>(
        inputs, w1, b1, w2, b2, out0, out1);
}